// Round 3
// baseline (414.025 us; speedup 1.0000x reference)
//
#include <hip/hip_runtime.h>
#include <cstdint>
#include <cstddef>

#define NB2 2048            // duration buckets (uniform [0,1))
#define NCELL (NB2 * 4)     // buckets x 4 causes
#define ALPHA 0.4
#define EPS 1e-8

// Workspace layout:
//   [0,128)    double acc[9]: [0..3] sum eta over events/cause, [4..7] sum log(denom)/cause, [8] CE sum
//   [128,144)  uint cnt[4]
//   [4096, 4096+nparts*32KB)  float partial[nparts][NCELL] (SoA: cell = c*NB2+b)
//   then       float histAoS[NCELL]  (AoS: [b*4+c])
//   then       float suffix[NCELL]   (AoS)

__device__ __forceinline__ float fcomp(const float4& f, int c) {
  return c == 0 ? f.x : c == 1 ? f.y : c == 2 ? f.z : f.w;
}

// ---------------- CE kernel: pure streaming over logits (160 MB) ----------------
__global__ __launch_bounds__(256) void ce_kernel(
    const float* __restrict__ logits, const int* __restrict__ lab,
    double* __restrict__ acc, int N)
{
  float ce = 0.f;
  const int stride = gridDim.x * 256;
  for (int i = blockIdx.x * 256 + threadIdx.x; i < N; i += stride) {
    const float4* pl = (const float4*)(logits + (size_t)i * 40);
    int lb = lab[i];
    float4 v[10];
#pragma unroll
    for (int j = 0; j < 10; ++j) v[j] = pl[j];   // 10 independent dwordx4 loads
    float L[5] = {0.f, 0.f, 0.f, 0.f, 0.f};
#pragma unroll
    for (int m = 0; m < 8; ++m)
#pragma unroll
      for (int k = 0; k < 5; ++k) {
        int idx = m * 5 + k;
        L[k] += fcomp(v[idx >> 2], idx & 3);     // constant-folded after unroll
      }
#pragma unroll
    for (int k = 0; k < 5; ++k) L[k] *= 0.125f;
    float mx = fmaxf(fmaxf(fmaxf(L[0], L[1]), fmaxf(L[2], L[3])), L[4]);
    float se = __expf(L[0] - mx) + __expf(L[1] - mx) + __expf(L[2] - mx) +
               __expf(L[3] - mx) + __expf(L[4] - mx);
    float lse = __logf(se) + mx;
    float lsel = (lb == 0) ? L[0] : (lb == 1) ? L[1] : (lb == 2) ? L[2]
               : (lb == 3) ? L[3] : L[4];
    ce += lsel - lse;
  }
  for (int o = 32; o; o >>= 1) ce += __shfl_down(ce, o);
  __shared__ float s_ce;
  if (threadIdx.x == 0) s_ce = 0.f;
  __syncthreads();
  if ((threadIdx.x & 63) == 0) atomicAdd(&s_ce, ce);
  __syncthreads();
  if (threadIdx.x == 0) unsafeAtomicAdd(&acc[8], (double)s_ce);
}

// ------------- Hazard kernel: log_h (128 MB) + dur/ev, LDS histogram -------------
__global__ __launch_bounds__(256) void hazard_kernel(
    const float* __restrict__ log_h, const float* __restrict__ dur,
    const int* __restrict__ ev, float* __restrict__ partial,
    double* __restrict__ acc, unsigned int* __restrict__ cnt, int N)
{
  __shared__ __align__(16) float h[NCELL];   // 32 KB private histogram, SoA
  __shared__ float s_f[4];
  __shared__ unsigned int s_u[4];
  const int t = threadIdx.x;
  for (int j = t; j < NCELL; j += 256) h[j] = 0.f;
  if (t < 4) { s_f[t] = 0.f; s_u[t] = 0u; }
  __syncthreads();

  float ea0 = 0.f, ea1 = 0.f, ea2 = 0.f, ea3 = 0.f;
  int c0 = 0, c1 = 0, c2 = 0, c3 = 0;

  const int stride = gridDim.x * 256;
  for (int i = blockIdx.x * 256 + t; i < N; i += stride) {
    const float4* ph = (const float4*)(log_h + (size_t)i * 32);
    float d = dur[i];
    int e = ev[i];
    float4 v[8];
#pragma unroll
    for (int m = 0; m < 8; ++m) v[m] = ph[m];   // 8 independent dwordx4 loads
    float m0 = 0.f, m1 = 0.f, m2 = 0.f, m3 = 0.f;
#pragma unroll
    for (int m = 0; m < 8; ++m) {
      m0 += v[m].x; m1 += v[m].y; m2 += v[m].z; m3 += v[m].w;
    }
    float e0 = fminf(fmaxf(m0 * 0.125f, -50.f), 50.f);
    float e1 = fminf(fmaxf(m1 * 0.125f, -50.f), 50.f);
    float e2 = fminf(fmaxf(m2 * 0.125f, -50.f), 50.f);
    float e3 = fminf(fmaxf(m3 * 0.125f, -50.f), 50.f);

    int b = (int)(d * (float)NB2);
    b = b < 0 ? 0 : (b > NB2 - 1 ? NB2 - 1 : b);
    atomicAdd(&h[0 * NB2 + b], __expf(e0));   // SoA: bank = b%32, conflict-light
    atomicAdd(&h[1 * NB2 + b], __expf(e1));
    atomicAdd(&h[2 * NB2 + b], __expf(e2));
    atomicAdd(&h[3 * NB2 + b], __expf(e3));

    ea0 += (e == 1) ? e0 : 0.f;  c0 += (e == 1);
    ea1 += (e == 2) ? e1 : 0.f;  c1 += (e == 2);
    ea2 += (e == 3) ? e2 : 0.f;  c2 += (e == 3);
    ea3 += (e == 4) ? e3 : 0.f;  c3 += (e == 4);
  }

#define WRED(v) { for (int o = 32; o; o >>= 1) v += __shfl_down(v, o); }
  WRED(ea0) WRED(ea1) WRED(ea2) WRED(ea3)
  WRED(c0) WRED(c1) WRED(c2) WRED(c3)
  if ((t & 63) == 0) {
    atomicAdd(&s_f[0], ea0); atomicAdd(&s_f[1], ea1);
    atomicAdd(&s_f[2], ea2); atomicAdd(&s_f[3], ea3);
    atomicAdd(&s_u[0], (unsigned)c0); atomicAdd(&s_u[1], (unsigned)c1);
    atomicAdd(&s_u[2], (unsigned)c2); atomicAdd(&s_u[3], (unsigned)c3);
  }
  __syncthreads();

  // flush private histogram: coalesced float4 stores, no atomics
  float4* out = (float4*)(partial + (size_t)blockIdx.x * NCELL);
  const float4* h4 = (const float4*)h;
  for (int j = t; j < NCELL / 4; j += 256) out[j] = h4[j];

  if (t < 4) {
    unsafeAtomicAdd(&acc[t], (double)s_f[t]);
    atomicAdd(&cnt[t], s_u[t]);
  }
}

// Fold nparts partial histograms (SoA) into one AoS histogram.
__global__ __launch_bounds__(256) void reduce_kernel(
    const float* __restrict__ partial, float* __restrict__ histAoS, int nparts)
{
  const int tc = threadIdx.x & 31;   // cell within block
  const int tp = threadIdx.x >> 5;   // partial-split 0..7
  const int cell = blockIdx.x * 32 + tc;
  float s = 0.f;
  for (int p = tp; p < nparts; p += 8)
    s += partial[(size_t)p * NCELL + cell];
  __shared__ float sh[256];
  sh[threadIdx.x] = s;
  __syncthreads();
  if (threadIdx.x < 32) {
    float v = 0.f;
#pragma unroll
    for (int k = 0; k < 8; ++k) v += sh[k * 32 + tc];
    int c = cell >> 11;        // cell = c*NB2 + b
    int b = cell & (NB2 - 1);
    histAoS[b * 4 + c] = v;
  }
}

// Inclusive suffix-sum over NB2 buckets (4 causes packed as float4). One WG.
__global__ __launch_bounds__(1024) void scan_kernel(
    const float* __restrict__ hist, float* __restrict__ suffix)
{
  const int CH = NB2 / 1024;   // 2
  const int t = threadIdx.x;
  __shared__ float4 part[1024];
  const float4* in = (const float4*)hist;
  float4* out = (float4*)suffix;

  float4 a = make_float4(0.f, 0.f, 0.f, 0.f);
  for (int j = 0; j < CH; ++j) {
    float4 v = in[t * CH + j];
    a.x += v.x; a.y += v.y; a.z += v.z; a.w += v.w;
  }
  part[t] = a;
  __syncthreads();
  for (int off = 1; off < 1024; off <<= 1) {
    float4 add = make_float4(0.f, 0.f, 0.f, 0.f);
    if (t + off < 1024) add = part[t + off];
    __syncthreads();
    float4 cur = part[t];
    cur.x += add.x; cur.y += add.y; cur.z += add.z; cur.w += add.w;
    part[t] = cur;
    __syncthreads();
  }
  float4 carry = (t < 1023) ? part[t + 1] : make_float4(0.f, 0.f, 0.f, 0.f);
  for (int j = CH - 1; j >= 0; --j) {
    float4 v = in[t * CH + j];
    carry.x += v.x; carry.y += v.y; carry.z += v.z; carry.w += v.w;
    out[t * CH + j] = carry;
  }
}

__global__ __launch_bounds__(256) void pass3_kernel(
    const float* __restrict__ dur, const int* __restrict__ ev,
    const float* __restrict__ suffix, double* __restrict__ acc, int N)
{
  const int t = threadIdx.x;
  float lg0 = 0.f, lg1 = 0.f, lg2 = 0.f, lg3 = 0.f;
  const int i = blockIdx.x * 256 + t;
  if (i < N) {
    int e = ev[i];
    if (e > 0) {
      float d = dur[i];
      int b = (int)(d * (float)NB2);
      b = b < 0 ? 0 : (b > NB2 - 1 ? NB2 - 1 : b);
      float lv = __logf(suffix[(size_t)b * 4 + (e - 1)] + (float)EPS);
      lg0 = (e == 1) ? lv : 0.f;
      lg1 = (e == 2) ? lv : 0.f;
      lg2 = (e == 3) ? lv : 0.f;
      lg3 = (e == 4) ? lv : 0.f;
    }
  }
  WRED(lg0) WRED(lg1) WRED(lg2) WRED(lg3)
  __shared__ float s_lg[4];
  if (t < 4) s_lg[t] = 0.f;
  __syncthreads();
  if ((t & 63) == 0) {
    atomicAdd(&s_lg[0], lg0); atomicAdd(&s_lg[1], lg1);
    atomicAdd(&s_lg[2], lg2); atomicAdd(&s_lg[3], lg3);
  }
  __syncthreads();
  if (t < 4 && s_lg[t] != 0.f) unsafeAtomicAdd(&acc[4 + t], (double)s_lg[t]);
}

__global__ void finalize_kernel(const double* __restrict__ acc,
                                const unsigned int* __restrict__ cnt,
                                float* __restrict__ out, int N)
{
  if (threadIdx.x == 0 && blockIdx.x == 0) {
    double ls = 0.0;
    for (int c = 0; c < 4; ++c) {
      double s = acc[c] - acc[4 + c];
      ls += -s / ((double)cnt[c] + EPS);
    }
    double ce = -acc[8] / (double)N;
    out[0] = (float)(ALPHA * ls + (1.0 - ALPHA) * ce);
  }
}

extern "C" void kernel_launch(void* const* d_in, const int* in_sizes, int n_in,
                              void* d_out, int out_size, void* d_ws, size_t ws_size,
                              hipStream_t stream) {
  const float* log_h  = (const float*)d_in[0];
  const float* logits = (const float*)d_in[1];
  const float* dur    = (const float*)d_in[2];
  const int*   ev     = (const int*)d_in[3];
  const int*   lab    = (const int*)d_in[4];
  const int N = in_sizes[2];

  const size_t cellBytes = (size_t)NCELL * sizeof(float);   // 32 KB
  size_t fixed = 4096 + 2 * cellBytes;
  int nparts = 1024;                      // 4 blocks/CU at 32 KB LDS
  if (ws_size > fixed) {
    size_t fit = (ws_size - fixed) / cellBytes;
    if ((size_t)nparts > fit) nparts = (int)fit;
  }
  if (nparts < 1) nparts = 1;

  char* ws = (char*)d_ws;
  double* acc = (double*)ws;
  unsigned int* cnt = (unsigned int*)(ws + 128);
  float* partial = (float*)(ws + 4096);
  float* histAoS = (float*)(ws + 4096 + (size_t)nparts * cellBytes);
  float* suffix  = (float*)(ws + 4096 + (size_t)nparts * cellBytes + cellBytes);

  hipMemsetAsync(ws, 0, 4096, stream);    // header only; everything else fully written

  hazard_kernel<<<nparts, 256, 0, stream>>>(log_h, dur, ev, partial, acc, cnt, N);
  ce_kernel<<<2048, 256, 0, stream>>>(logits, lab, acc, N);
  reduce_kernel<<<256, 256, 0, stream>>>(partial, histAoS, nparts);
  scan_kernel<<<1, 1024, 0, stream>>>(histAoS, suffix);
  const int nb = (N + 255) / 256;
  pass3_kernel<<<nb, 256, 0, stream>>>(dur, ev, suffix, acc, N);
  finalize_kernel<<<1, 1, 0, stream>>>(acc, cnt, (float*)d_out, N);
}